// Round 16
// baseline (413.075 us; speedup 1.0000x reference)
//
#include <hip/hip_runtime.h>
#include <stdint.h>

typedef _Float16 half2_t __attribute__((ext_vector_type(2)));
typedef short bf16x8 __attribute__((ext_vector_type(8)));
typedef float f32x4 __attribute__((ext_vector_type(4)));
typedef int i32x4 __attribute__((ext_vector_type(4)));
typedef int i32x8 __attribute__((ext_vector_type(8)));
typedef unsigned short u16;
typedef unsigned int u32;
typedef unsigned long long u64;

#define B_ 64
#define S_ 512
#define D_ 512
#define H_ 512
#define FF_ 1024
#define C_ 1000
#define V_ 32000

// scaling: W' = 128*Wh (fp4 e2m1), g = 256*h (fp4, >=0), tail W'' = 16*W (fp8).
#define SW4 128.0f
#define SH4 256.0f
#define SWT 16.0f

__device__ __forceinline__ u16 f2bf(float f){
  u32 u = __builtin_bit_cast(u32, f);
  u = (u + 0x7FFFu + ((u >> 16) & 1u)) >> 16;
  return (u16)u;
}
__device__ __forceinline__ u32 pkbf(float a, float b){
  return (u32)f2bf(a) | ((u32)f2bf(b) << 16);
}
__device__ __forceinline__ u32 packh2(float a, float b){
  u16 lo = __builtin_bit_cast(u16, (_Float16)a);
  u16 hi = __builtin_bit_cast(u16, (_Float16)b);
  return (u32)lo | ((u32)hi << 16);
}
__device__ __forceinline__ float fdot2u(u32 a, u32 b, float c){
  return __builtin_amdgcn_fdot2(__builtin_bit_cast(half2_t, a),
                                __builtin_bit_cast(half2_t, b), c, false);
}
__device__ __forceinline__ float h2f(u16 h){
  return (float)__builtin_bit_cast(_Float16, h);
}
__device__ __forceinline__ float fp4val(u32 c){
  int e = (c >> 1) & 3;
  float m = 1.0f + 0.5f * (float)(c & 1);
  return (e == 0) ? 0.5f * (float)(c & 1) : m * (float)(1 << (e - 1));
}

// ---- P: Wx transpose+cvt [0,64) | Wh fp4 fragments [64,96) ----
__global__ void k_prep(const float* __restrict__ Wx, u16* __restrict__ WxT,
                       const float* __restrict__ Wh, uint4* __restrict__ Wf4){
  __shared__ u16 t[64][65];
  int bid = blockIdx.x, tid = threadIdx.x;
  if (bid < 64){
    int bx = bid & 7, by = bid >> 3;
    int c = tid & 63, r0 = (tid >> 6) * 16;
    #pragma unroll
    for (int i = 0; i < 16; i++){
      int k = by * 64 + r0 + i, n = bx * 64 + c;
      t[r0 + i][c] = f2bf(Wx[k * 512 + n]);
    }
    __syncthreads();
    #pragma unroll
    for (int i = 0; i < 16; i++){
      int n = bx * 64 + r0 + i, k = by * 64 + c;
      WxT[n * 512 + k] = t[c][r0 + i];
    }
  } else {
    int g = (bid - 64) * 256 + tid;            // 8192
    int fidx = g >> 6, l = g & 63;
    int wv = fidx >> 4, ct = (fidx >> 2) & 3, kt = fidx & 3;
    int q = l >> 4, n = wv * 64 + ct * 16 + (l & 15);
    int k0 = kt * 128 + q * 32;
    u32 d[4] = {0u, 0u, 0u, 0u};
    #pragma unroll
    for (int j = 0; j < 32; j++){
      float w = Wh[(size_t)(k0 + j) * 512 + n] * SW4;
      float aw = fabsf(w);
      u32 s = (w < 0.f) ? 8u : 0u;
      u32 c;
      if (aw < 2.f) c = (u32)(int)rintf(aw * 2.f);
      else if (aw < 4.f) c = 4u + (u32)(int)rintf(aw - 2.f);
      else { c = 6u + (u32)(int)rintf((aw - 4.f) * 0.5f); if (c > 7u) c = 7u; }
      d[j >> 3] |= (c | s) << (4 * (j & 7));
    }
    uint4 o; o.x = d[0]; o.y = d[1]; o.z = d[2]; o.w = d[3];
    Wf4[(size_t)fidx * 64 + l] = o;
  }
}

// ---- G: vocab GEMM [0,500) + fp8 weight packs [500,1768) ----
// W1q [500,756): u32 = fp8{W1[2p][2c],W1[2p+1][2c],W1[2p][2c+1],W1[2p+1][2c+1]}*16
// W2q [756,1268), Woq [1268,1768) same layout (Wo has 500 col-pairs).
__global__ __launch_bounds__(512) void k_gemm(const float* __restrict__ emb,
                                              const u16* __restrict__ WxT,
                                              const float* __restrict__ bias,
                                              u16* __restrict__ xpV,
                                              const float* __restrict__ W1, u32* __restrict__ W1q,
                                              const float* __restrict__ W2, u32* __restrict__ W2q,
                                              const float* __restrict__ Wo, u32* __restrict__ Woq){
  __shared__ __align__(16) u16 As[64 * 40];
  int bid = blockIdx.x, tid = threadIdx.x;
  if (bid >= 500){
    if (bid < 756){
      int i = (bid - 500) * 512 + tid;         // 131072 = 256p x 512cp
      int p = i >> 9, cp = i & 511;
      float w00 = W1[(2 * p) * FF_ + 2 * cp] * SWT;
      float w10 = W1[(2 * p + 1) * FF_ + 2 * cp] * SWT;
      float w01 = W1[(2 * p) * FF_ + 2 * cp + 1] * SWT;
      float w11 = W1[(2 * p + 1) * FF_ + 2 * cp + 1] * SWT;
      u32 pk = __builtin_amdgcn_cvt_pk_fp8_f32(w00, w10, 0, false);
      pk = __builtin_amdgcn_cvt_pk_fp8_f32(w01, w11, pk, true);
      W1q[p * 512 + cp] = pk;
    } else if (bid < 1268){
      int i = (bid - 756) * 512 + tid;         // 262144 = 512p x 512cp
      int p = i >> 9, cp = i & 511;
      float w00 = W2[(2 * p) * FF_ + 2 * cp] * SWT;
      float w10 = W2[(2 * p + 1) * FF_ + 2 * cp] * SWT;
      float w01 = W2[(2 * p) * FF_ + 2 * cp + 1] * SWT;
      float w11 = W2[(2 * p + 1) * FF_ + 2 * cp + 1] * SWT;
      u32 pk = __builtin_amdgcn_cvt_pk_fp8_f32(w00, w10, 0, false);
      pk = __builtin_amdgcn_cvt_pk_fp8_f32(w01, w11, pk, true);
      W2q[p * 512 + cp] = pk;
    } else {
      int i = (bid - 1268) * 512 + tid;        // 256000 = 512p x 500cp
      if (i < 256000){
        int p = i / 500, cp = i - p * 500;
        float w00 = Wo[(2 * p) * C_ + 2 * cp] * SWT;
        float w10 = Wo[(2 * p + 1) * C_ + 2 * cp] * SWT;
        float w01 = Wo[(2 * p) * C_ + 2 * cp + 1] * SWT;
        float w11 = Wo[(2 * p + 1) * C_ + 2 * cp + 1] * SWT;
        u32 pk = __builtin_amdgcn_cvt_pk_fp8_f32(w00, w10, 0, false);
        pk = __builtin_amdgcn_cvt_pk_fp8_f32(w01, w11, pk, true);
        Woq[p * 500 + cp] = pk;
      }
    }
    return;
  }
  int m0 = bid * 64;
  int w = tid >> 6, l = tid & 63, kg = l >> 4, r16 = l & 15;
  const u16* bptr[4];
  #pragma unroll
  for (int ni = 0; ni < 4; ni++)
    bptr[ni] = WxT + (size_t)(w * 64 + ni * 16 + r16) * 512 + kg * 8;
  f32x4 acc[4][4];
  #pragma unroll
  for (int mi = 0; mi < 4; mi++)
    #pragma unroll
    for (int ni = 0; ni < 4; ni++) acc[mi][ni] = (f32x4){0.f, 0.f, 0.f, 0.f};
  int srow = tid >> 3, sk = (tid & 7) * 4;
  const float* ebase = emb + (size_t)(m0 + srow) * 512 + sk;
  float4 f = *(const float4*)ebase;            // kt = 0
  for (int kt = 0; kt < 16; kt++){
    u32 lo = pkbf(f.x, f.y), hi = pkbf(f.z, f.w);
    float4 fn;
    if (kt < 15) fn = *(const float4*)(ebase + (kt + 1) * 32);   // prefetch
    __syncthreads();
    uint2 st; st.x = lo; st.y = hi;
    *(uint2*)(As + srow * 40 + sk) = st;
    __syncthreads();
    bf16x8 bfr[4], af[4];
    #pragma unroll
    for (int ni = 0; ni < 4; ni++)
      bfr[ni] = *(const bf16x8*)(bptr[ni] + kt * 32);
    #pragma unroll
    for (int mi = 0; mi < 4; mi++)
      af[mi] = *(const bf16x8*)(As + (mi * 16 + r16) * 40 + kg * 8);
    #pragma unroll
    for (int mi = 0; mi < 4; mi++)
      #pragma unroll
      for (int ni = 0; ni < 4; ni++)
        acc[mi][ni] = __builtin_amdgcn_mfma_f32_16x16x32_bf16(af[mi], bfr[ni], acc[mi][ni], 0, 0, 0);
    f = fn;
  }
  #pragma unroll
  for (int ni = 0; ni < 4; ni++){
    int col = w * 64 + ni * 16 + r16;
    float bb = bias[col];
    #pragma unroll
    for (int mi = 0; mi < 4; mi++){
      int mb = m0 + mi * 16 + kg * 4;
      #pragma unroll
      for (int r = 0; r < 4; r++){
        float v = (acc[mi][ni][r] + bb) * SH4;
        xpV[(size_t)(mb + r) * 512 + col] = __builtin_bit_cast(u16, (_Float16)v);
      }
    }
  }
}

// ---- R: 512-step RNN scan (R11 core, control) + fused tail v3 (fp8 wts). ----
__global__ __launch_bounds__(512, 2) void k_rnnt(
    const uint4* __restrict__ Wf4, const u16* __restrict__ xpV,
    const int* __restrict__ tokens,
    const u32* __restrict__ W1q, const float* __restrict__ b1,
    const u32* __restrict__ W2q, const float* __restrict__ b2,
    const u32* __restrict__ Woq, const float* __restrict__ bo,
    float* __restrict__ out){
  __shared__ __align__(16) unsigned char gA[256];
  __shared__ __align__(16) unsigned char gB[256];
  __shared__ int toks[512];
  __shared__ __align__(16) float fb1[1024];
  __shared__ __align__(16) float fb2[1024];
  __shared__ float redm[8], reds[8];
  int b = blockIdx.x, tid = threadIdx.x;
  int wv = tid >> 6, l = tid & 63, q = l >> 4, n16 = l & 15;
  int col = wv * 64 + q * 16 + n16;

  i32x8 wgt[16];
  #pragma unroll
  for (int ct = 0; ct < 4; ct++)
    #pragma unroll
    for (int kt = 0; kt < 4; kt++){
      int fidx = (wv * 4 + ct) * 4 + kt;
      uint4 wl = Wf4[(size_t)fidx * 64 + l];
      i32x8 w8 = {(int)wl.x, (int)wl.y, (int)wl.z, (int)wl.w, 0, 0, 0, 0};
      wgt[ct * 4 + kt] = w8;
    }

  toks[tid] = tokens[b * 512 + tid];
  if (tid < 64) ((u32*)gA)[tid] = 0;
  __syncthreads();

  const u16* xpc = xpV + col;                  // lane's column base
  u16 xraw = xpc[(size_t)toks[0] * 512];
  u32 greg = 0;

#define RNN_STEP(T, SRC, DST)                                                 \
  {                                                                           \
    int tn = toks[(T + 1) & 511];                                             \
    u16 xnext = xpc[(size_t)tn * 512];                                        \
    bool wr = toks[T] != 0;                                                   \
    i32x4 av0 = *(const i32x4*)(SRC + 0 * 64 + q * 16);                       \
    i32x4 av1 = *(const i32x4*)(SRC + 1 * 64 + q * 16);                       \
    i32x4 av2 = *(const i32x4*)(SRC + 2 * 64 + q * 16);                       \
    i32x4 av3 = *(const i32x4*)(SRC + 3 * 64 + q * 16);                       \
    i32x8 a80 = {av0[0], av0[1], av0[2], av0[3], 0, 0, 0, 0};                 \
    i32x8 a81 = {av1[0], av1[1], av1[2], av1[3], 0, 0, 0, 0};                 \
    i32x8 a82 = {av2[0], av2[1], av2[2], av2[3], 0, 0, 0, 0};                 \
    i32x8 a83 = {av3[0], av3[1], av3[2], av3[3], 0, 0, 0, 0};                 \
    f32x4 acc0 = {0.f,0.f,0.f,0.f}, acc1 = {0.f,0.f,0.f,0.f};                 \
    f32x4 acc2 = {0.f,0.f,0.f,0.f}, acc3 = {0.f,0.f,0.f,0.f};                 \
    __builtin_amdgcn_s_setprio(1);                                            \
    acc0 = __builtin_amdgcn_mfma_scale_f32_16x16x128_f8f6f4(a80, wgt[0],  acc0, 4, 4, 0, 127, 0, 127); \
    acc1 = __builtin_amdgcn_mfma_scale_f32_16x16x128_f8f6f4(a80, wgt[4],  acc1, 4, 4, 0, 127, 0, 127); \
    acc2 = __builtin_amdgcn_mfma_scale_f32_16x16x128_f8f6f4(a80, wgt[8],  acc2, 4, 4, 0, 127, 0, 127); \
    acc3 = __builtin_amdgcn_mfma_scale_f32_16x16x128_f8f6f4(a80, wgt[12], acc3, 4, 4, 0, 127, 0, 127); \
    acc0 = __builtin_amdgcn_mfma_scale_f32_16x16x128_f8f6f4(a81, wgt[1],  acc0, 4, 4, 0, 127, 0, 127); \
    acc1 = __builtin_amdgcn_mfma_scale_f32_16x16x128_f8f6f4(a81, wgt[5],  acc1, 4, 4, 0, 127, 0, 127); \
    acc2 = __builtin_amdgcn_mfma_scale_f32_16x16x128_f8f6f4(a81, wgt[9],  acc2, 4, 4, 0, 127, 0, 127); \
    acc3 = __builtin_amdgcn_mfma_scale_f32_16x16x128_f8f6f4(a81, wgt[13], acc3, 4, 4, 0, 127, 0, 127); \
    acc0 = __builtin_amdgcn_mfma_scale_f32_16x16x128_f8f6f4(a82, wgt[2],  acc0, 4, 4, 0, 127, 0, 127); \
    acc1 = __builtin_amdgcn_mfma_scale_f32_16x16x128_f8f6f4(a82, wgt[6],  acc1, 4, 4, 0, 127, 0, 127); \
    acc2 = __builtin_amdgcn_mfma_scale_f32_16x16x128_f8f6f4(a82, wgt[10], acc2, 4, 4, 0, 127, 0, 127); \
    acc3 = __builtin_amdgcn_mfma_scale_f32_16x16x128_f8f6f4(a82, wgt[14], acc3, 4, 4, 0, 127, 0, 127); \
    acc0 = __builtin_amdgcn_mfma_scale_f32_16x16x128_f8f6f4(a83, wgt[3],  acc0, 4, 4, 0, 127, 0, 127); \
    acc1 = __builtin_amdgcn_mfma_scale_f32_16x16x128_f8f6f4(a83, wgt[7],  acc1, 4, 4, 0, 127, 0, 127); \
    acc2 = __builtin_amdgcn_mfma_scale_f32_16x16x128_f8f6f4(a83, wgt[11], acc2, 4, 4, 0, 127, 0, 127); \
    acc3 = __builtin_amdgcn_mfma_scale_f32_16x16x128_f8f6f4(a83, wgt[15], acc3, 4, 4, 0, 127, 0, 127); \
    __builtin_amdgcn_s_setprio(0);                                            \
    float av = (q == 0) ? acc0[0] : (q == 1) ? acc1[0] : (q == 2) ? acc2[0] : acc3[0]; \
    float gn = fmaxf(fmaf(av, 1.0f / SW4, h2f(xraw)), 0.f);                   \
    u32 code;                                                                 \
    if (gn < 2.f) code = (u32)(int)rintf(gn * 2.f);                           \
    else if (gn < 4.f) code = 4u + (u32)(int)rintf(gn - 2.f);                 \
    else { u32 c = 6u + (u32)(int)rintf((gn - 4.f) * 0.5f); code = c > 7u ? 7u : c; } \
    u32 pc = (u32)__shfl_xor((int)code, 1);                                   \
    u32 byte = (n16 & 1) ? (pc | (code << 4)) : (code | (pc << 4));           \
    if (wr) greg = byte;                                                      \
    if ((l & 1) == 0) DST[col >> 1] = (unsigned char)greg;                    \
    xraw = xnext;                                                             \
  }

  #pragma unroll 1
  for (int t = 0; t < 512; t += 2){
    RNN_STEP(t, gA, gB);
    __syncthreads();
    RNN_STEP(t + 1, gB, gA);
    __syncthreads();
  }
#undef RNN_STEP

  // ---- fused per-batch tail v3: fp8 weights, f32 activations ----
  // decode final h (fp4 in gA) into f32: fb2[0..511]
  if (tid < 256){
    u32 byte = gA[tid];
    fb2[2 * tid] = fp4val(byte & 15u) * (1.0f / SH4);
    fb2[2 * tid + 1] = fp4val(byte >> 4) * (1.0f / SH4);
  }
  __syncthreads();

  int n0 = 2 * tid;                            // adjacent output columns

  // fc1: K=512 (256 u32) from fb2 -> fb1[1024]
  {
    float a0 = 0.f, a1 = 0.f;
    #pragma unroll 4
    for (int p = 0; p < 256; p++){
      u32 w = W1q[p * 512 + tid];
      float2 hv = *(const float2*)&fb2[2 * p];
      a0 = fmaf(__builtin_amdgcn_cvt_f32_fp8(w, 0), hv.x, a0);
      a0 = fmaf(__builtin_amdgcn_cvt_f32_fp8(w, 1), hv.y, a0);
      a1 = fmaf(__builtin_amdgcn_cvt_f32_fp8(w, 2), hv.x, a1);
      a1 = fmaf(__builtin_amdgcn_cvt_f32_fp8(w, 3), hv.y, a1);
    }
    fb1[n0] = fmaxf(fmaf(a0, 1.0f / SWT, b1[n0]), 0.f);
    fb1[n0 + 1] = fmaxf(fmaf(a1, 1.0f / SWT, b1[n0 + 1]), 0.f);
  }
  __syncthreads();

  // fc2: K=1024 (512 u32) from fb1 -> fb2[1024]
  {
    float a0 = 0.f, a1 = 0.f;
    #pragma unroll 4
    for (int p = 0; p < 512; p++){
      u32 w = W2q[p * 512 + tid];
      float2 hv = *(const float2*)&fb1[2 * p];
      a0 = fmaf(__builtin_amdgcn_cvt_f32_fp8(w, 0), hv.x, a0);
      a0 = fmaf(__builtin_amdgcn_cvt_f32_fp8(w, 1), hv.y, a0);
      a1 = fmaf(__builtin_amdgcn_cvt_f32_fp8(w, 2), hv.x, a1);
      a1 = fmaf(__builtin_amdgcn_cvt_f32_fp8(w, 3), hv.y, a1);
    }
    fb2[n0] = fmaxf(fmaf(a0, 1.0f / SWT, b2[n0]), 0.f);
    fb2[n0 + 1] = fmaxf(fmaf(a1, 1.0f / SWT, b2[n0 + 1]), 0.f);
  }
  __syncthreads();

  // outz + softmax: thread tid<500 owns logits n0, n0+1
  {
    bool act = tid < 500;
    float z0 = 0.f, z1 = 0.f;
    if (act){
      #pragma unroll 4
      for (int p = 0; p < 512; p++){
        u32 w = Woq[p * 500 + tid];
        float2 hv = *(const float2*)&fb2[2 * p];
        z0 = fmaf(__builtin_amdgcn_cvt_f32_fp8(w, 0), hv.x, z0);
        z0 = fmaf(__builtin_amdgcn_cvt_f32_fp8(w, 1), hv.y, z0);
        z1 = fmaf(__builtin_amdgcn_cvt_f32_fp8(w, 2), hv.x, z1);
        z1 = fmaf(__builtin_amdgcn_cvt_f32_fp8(w, 3), hv.y, z1);
      }
      z0 = fmaf(z0, 1.0f / SWT, bo[n0]);
      z1 = fmaf(z1, 1.0f / SWT, bo[n0 + 1]);
    }
    float mx = act ? fmaxf(z0, z1) : -1e30f;
    #pragma unroll
    for (int o = 1; o < 64; o <<= 1) mx = fmaxf(mx, __shfl_xor(mx, o));
    if ((tid & 63) == 0) redm[wv] = mx;
    __syncthreads();
    mx = redm[0];
    #pragma unroll
    for (int i = 1; i < 8; i++) mx = fmaxf(mx, redm[i]);
    float e0 = act ? __expf(z0 - mx) : 0.f;
    float e1 = act ? __expf(z1 - mx) : 0.f;
    float s = e0 + e1;
    #pragma unroll
    for (int o = 1; o < 64; o <<= 1) s += __shfl_xor(s, o);
    if ((tid & 63) == 0) reds[wv] = s;
    __syncthreads();
    s = 0.f;
    #pragma unroll
    for (int i = 0; i < 8; i++) s += reds[i];
    float inv = 1.0f / s;
    if (act){
      out[(size_t)b * C_ + n0] = e0 * inv;
      out[(size_t)b * C_ + n0 + 1] = e1 * inv;
    }
  }
}

extern "C" void kernel_launch(void* const* d_in, const int* in_sizes, int n_in,
                              void* d_out, int out_size, void* d_ws, size_t ws_size,
                              hipStream_t stream) {
  const int*   tokens = (const int*)d_in[0];
  const float* emb    = (const float*)d_in[1];
  const float* Wx     = (const float*)d_in[2];
  const float* Wh     = (const float*)d_in[3];
  const float* brnn   = (const float*)d_in[4];
  const float* W1     = (const float*)d_in[5];
  const float* b1     = (const float*)d_in[6];
  const float* W2     = (const float*)d_in[7];
  const float* b2     = (const float*)d_in[8];
  const float* Wo     = (const float*)d_in[9];
  const float* bo     = (const float*)d_in[10];
  float* out = (float*)d_out;

  char* ws = (char*)d_ws;
  size_t off = 0;
  auto alloc = [&](size_t bytes) -> void* {
    void* p = ws + off;
    off += (bytes + 255) & ~(size_t)255;
    return p;
  };
  u16* WxT    = (u16*)alloc((size_t)512 * 512 * 2);
  u16* xpV    = (u16*)alloc((size_t)V_ * 512 * 2);
  uint4* Wf4  = (uint4*)alloc((size_t)128 * 64 * 16);
  u32* W1q    = (u32*)alloc((size_t)256 * 512 * 4);     // fp8-packed W1
  u32* W2q    = (u32*)alloc((size_t)512 * 512 * 4);     // fp8-packed W2
  u32* Woq    = (u32*)alloc((size_t)512 * 500 * 4);     // fp8-packed Wo

  k_prep<<<dim3(96), dim3(256), 0, stream>>>(Wx, WxT, Wh, Wf4);
  k_gemm<<<dim3(1768), dim3(512), 0, stream>>>(emb, WxT, brnn, xpV,
                                               W1, W1q, W2, W2q, Wo, Woq);
  k_rnnt<<<dim3(64), dim3(512), 0, stream>>>(Wf4, xpV, tokens,
                                             W1q, b1, W2q, b2, Woq, bo, out);
}

// Round 17
// 362.306 us; speedup vs baseline: 1.1401x; 1.1401x over previous
//
#include <hip/hip_runtime.h>
#include <stdint.h>

typedef _Float16 half2_t __attribute__((ext_vector_type(2)));
typedef short bf16x8 __attribute__((ext_vector_type(8)));
typedef float f32x4 __attribute__((ext_vector_type(4)));
typedef int i32x4 __attribute__((ext_vector_type(4)));
typedef int i32x8 __attribute__((ext_vector_type(8)));
typedef unsigned short u16;
typedef unsigned int u32;
typedef unsigned long long u64;

#define B_ 64
#define S_ 512
#define D_ 512
#define H_ 512
#define FF_ 1024
#define C_ 1000
#define V_ 32000

// scaling: W' = 128*Wh (fp4 e2m1), g = 256*h (fp4, >=0).
// tail: weights i8 x1024; activations i8 (h x4096 exact, y1/y2 x8192).
#define SW4 128.0f
#define SH4 256.0f

__device__ __forceinline__ u16 f2bf(float f){
  u32 u = __builtin_bit_cast(u32, f);
  u = (u + 0x7FFFu + ((u >> 16) & 1u)) >> 16;
  return (u16)u;
}
__device__ __forceinline__ u32 pkbf(float a, float b){
  return (u32)f2bf(a) | ((u32)f2bf(b) << 16);
}
__device__ __forceinline__ u32 packh2(float a, float b){
  u16 lo = __builtin_bit_cast(u16, (_Float16)a);
  u16 hi = __builtin_bit_cast(u16, (_Float16)b);
  return (u32)lo | ((u32)hi << 16);
}
__device__ __forceinline__ float h2f(u16 h){
  return (float)__builtin_bit_cast(_Float16, h);
}
__device__ __forceinline__ float fp4val(u32 c){
  int e = (c >> 1) & 3;
  float m = 1.0f + 0.5f * (float)(c & 1);
  return (e == 0) ? 0.5f * (float)(c & 1) : m * (float)(1 << (e - 1));
}
// fp4 code (0..7) -> i8 of 4096*h = 16*fp4val, exact: {0,8,16,24,32,48,64,96}
__device__ __forceinline__ u32 fp4i8(u32 c){
  u32 e = (c >> 1) & 3;
  return e ? (2u + (c & 1u)) * (4u << e) : 8u * (c & 1u);
}
__device__ __forceinline__ int dot4(u32 a, u32 b, int c){
  return __builtin_amdgcn_sdot4((int)a, (int)b, c, false);
}
__device__ __forceinline__ u32 q8(float w){
  int q = (int)fminf(fmaxf(rintf(w), -127.f), 127.f);
  return (u32)(q & 0xFF);
}

// ---- P: Wx transpose+cvt [0,64) | Wh fp4 fragments [64,96) ----
__global__ void k_prep(const float* __restrict__ Wx, u16* __restrict__ WxT,
                       const float* __restrict__ Wh, uint4* __restrict__ Wf4){
  __shared__ u16 t[64][65];
  int bid = blockIdx.x, tid = threadIdx.x;
  if (bid < 64){
    int bx = bid & 7, by = bid >> 3;
    int c = tid & 63, r0 = (tid >> 6) * 16;
    #pragma unroll
    for (int i = 0; i < 16; i++){
      int k = by * 64 + r0 + i, n = bx * 64 + c;
      t[r0 + i][c] = f2bf(Wx[k * 512 + n]);
    }
    __syncthreads();
    #pragma unroll
    for (int i = 0; i < 16; i++){
      int n = bx * 64 + r0 + i, k = by * 64 + c;
      WxT[n * 512 + k] = t[c][r0 + i];
    }
  } else {
    int g = (bid - 64) * 256 + tid;            // 8192
    int fidx = g >> 6, l = g & 63;
    int wv = fidx >> 4, ct = (fidx >> 2) & 3, kt = fidx & 3;
    int q = l >> 4, n = wv * 64 + ct * 16 + (l & 15);
    int k0 = kt * 128 + q * 32;
    u32 d[4] = {0u, 0u, 0u, 0u};
    #pragma unroll
    for (int j = 0; j < 32; j++){
      float w = Wh[(size_t)(k0 + j) * 512 + n] * SW4;
      float aw = fabsf(w);
      u32 s = (w < 0.f) ? 8u : 0u;
      u32 c;
      if (aw < 2.f) c = (u32)(int)rintf(aw * 2.f);
      else if (aw < 4.f) c = 4u + (u32)(int)rintf(aw - 2.f);
      else { c = 6u + (u32)(int)rintf((aw - 4.f) * 0.5f); if (c > 7u) c = 7u; }
      d[j >> 3] |= (c | s) << (4 * (j & 7));
    }
    uint4 o; o.x = d[0]; o.y = d[1]; o.z = d[2]; o.w = d[3];
    Wf4[(size_t)fidx * 64 + l] = o;
  }
}

// ---- G: vocab GEMM [0,500) + i8 weight packs [500,1768) ----
// W1i [500,756): u32 = i8{W1[4g+j][n]}*1024, j=0..3. [128g][1024n]
// W2i [756,1268): [256g][1024n].  Woi [1268,1768): [256g][1000n].
__global__ __launch_bounds__(512) void k_gemm(const float* __restrict__ emb,
                                              const u16* __restrict__ WxT,
                                              const float* __restrict__ bias,
                                              u16* __restrict__ xpV,
                                              const float* __restrict__ W1, u32* __restrict__ W1i,
                                              const float* __restrict__ W2, u32* __restrict__ W2i,
                                              const float* __restrict__ Wo, u32* __restrict__ Woi){
  __shared__ __align__(16) u16 As[64 * 40];
  int bid = blockIdx.x, tid = threadIdx.x;
  if (bid >= 500){
    if (bid < 756){
      int i = (bid - 500) * 512 + tid;         // 131072 = 128g x 1024n
      int g = i >> 10, n = i & 1023;
      u32 pk = 0;
      #pragma unroll
      for (int j = 0; j < 4; j++)
        pk |= q8(W1[(4 * g + j) * FF_ + n] * 1024.f) << (8 * j);
      W1i[g * 1024 + n] = pk;
    } else if (bid < 1268){
      int i = (bid - 756) * 512 + tid;         // 262144 = 256g x 1024n
      int g = i >> 10, n = i & 1023;
      u32 pk = 0;
      #pragma unroll
      for (int j = 0; j < 4; j++)
        pk |= q8(W2[(4 * g + j) * FF_ + n] * 1024.f) << (8 * j);
      W2i[g * 1024 + n] = pk;
    } else {
      int i = (bid - 1268) * 512 + tid;        // 256000 = 256g x 1000n
      int g = i / 1000, n = i - g * 1000;
      u32 pk = 0;
      #pragma unroll
      for (int j = 0; j < 4; j++)
        pk |= q8(Wo[(4 * g + j) * C_ + n] * 1024.f) << (8 * j);
      Woi[g * 1000 + n] = pk;
    }
    return;
  }
  int m0 = bid * 64;
  int w = tid >> 6, l = tid & 63, kg = l >> 4, r16 = l & 15;
  const u16* bptr[4];
  #pragma unroll
  for (int ni = 0; ni < 4; ni++)
    bptr[ni] = WxT + (size_t)(w * 64 + ni * 16 + r16) * 512 + kg * 8;
  f32x4 acc[4][4];
  #pragma unroll
  for (int mi = 0; mi < 4; mi++)
    #pragma unroll
    for (int ni = 0; ni < 4; ni++) acc[mi][ni] = (f32x4){0.f, 0.f, 0.f, 0.f};
  int srow = tid >> 3, sk = (tid & 7) * 4;
  const float* ebase = emb + (size_t)(m0 + srow) * 512 + sk;
  float4 f = *(const float4*)ebase;            // kt = 0
  for (int kt = 0; kt < 16; kt++){
    u32 lo = pkbf(f.x, f.y), hi = pkbf(f.z, f.w);
    float4 fn;
    if (kt < 15) fn = *(const float4*)(ebase + (kt + 1) * 32);   // prefetch
    __syncthreads();
    uint2 st; st.x = lo; st.y = hi;
    *(uint2*)(As + srow * 40 + sk) = st;
    __syncthreads();
    bf16x8 bfr[4], af[4];
    #pragma unroll
    for (int ni = 0; ni < 4; ni++)
      bfr[ni] = *(const bf16x8*)(bptr[ni] + kt * 32);
    #pragma unroll
    for (int mi = 0; mi < 4; mi++)
      af[mi] = *(const bf16x8*)(As + (mi * 16 + r16) * 40 + kg * 8);
    #pragma unroll
    for (int mi = 0; mi < 4; mi++)
      #pragma unroll
      for (int ni = 0; ni < 4; ni++)
        acc[mi][ni] = __builtin_amdgcn_mfma_f32_16x16x32_bf16(af[mi], bfr[ni], acc[mi][ni], 0, 0, 0);
    f = fn;
  }
  #pragma unroll
  for (int ni = 0; ni < 4; ni++){
    int col = w * 64 + ni * 16 + r16;
    float bb = bias[col];
    #pragma unroll
    for (int mi = 0; mi < 4; mi++){
      int mb = m0 + mi * 16 + kg * 4;
      #pragma unroll
      for (int r = 0; r < 4; r++){
        float v = (acc[mi][ni][r] + bb) * SH4;
        xpV[(size_t)(mb + r) * 512 + col] = __builtin_bit_cast(u16, (_Float16)v);
      }
    }
  }
}

// ---- R: 512-step RNN scan (R11 core, control) + fused tail v4 (i8 dot4). ----
__global__ __launch_bounds__(512, 2) void k_rnnt(
    const uint4* __restrict__ Wf4, const u16* __restrict__ xpV,
    const int* __restrict__ tokens,
    const u32* __restrict__ W1i, const float* __restrict__ b1,
    const u32* __restrict__ W2i, const float* __restrict__ b2,
    const u32* __restrict__ Woi, const float* __restrict__ bo,
    float* __restrict__ out){
  __shared__ __align__(16) unsigned char gA[256];
  __shared__ __align__(16) unsigned char gB[256];
  __shared__ int toks[512];
  __shared__ __align__(16) u32 hi8[128];
  __shared__ __align__(16) u32 y1i8[256];
  __shared__ __align__(16) u32 y2i8[256];
  __shared__ float redm[8], reds[8];
  int b = blockIdx.x, tid = threadIdx.x;
  int wv = tid >> 6, l = tid & 63, q = l >> 4, n16 = l & 15;
  int col = wv * 64 + q * 16 + n16;

  i32x8 wgt[16];
  #pragma unroll
  for (int ct = 0; ct < 4; ct++)
    #pragma unroll
    for (int kt = 0; kt < 4; kt++){
      int fidx = (wv * 4 + ct) * 4 + kt;
      uint4 wl = Wf4[(size_t)fidx * 64 + l];
      i32x8 w8 = {(int)wl.x, (int)wl.y, (int)wl.z, (int)wl.w, 0, 0, 0, 0};
      wgt[ct * 4 + kt] = w8;
    }

  toks[tid] = tokens[b * 512 + tid];
  if (tid < 64) ((u32*)gA)[tid] = 0;
  __syncthreads();

  const u16* xpc = xpV + col;                  // lane's column base
  u16 xraw = xpc[(size_t)toks[0] * 512];
  u32 greg = 0;

#define RNN_STEP(T, SRC, DST)                                                 \
  {                                                                           \
    int tn = toks[(T + 1) & 511];                                             \
    u16 xnext = xpc[(size_t)tn * 512];                                        \
    bool wr = toks[T] != 0;                                                   \
    i32x4 av0 = *(const i32x4*)(SRC + 0 * 64 + q * 16);                       \
    i32x4 av1 = *(const i32x4*)(SRC + 1 * 64 + q * 16);                       \
    i32x4 av2 = *(const i32x4*)(SRC + 2 * 64 + q * 16);                       \
    i32x4 av3 = *(const i32x4*)(SRC + 3 * 64 + q * 16);                       \
    i32x8 a80 = {av0[0], av0[1], av0[2], av0[3], 0, 0, 0, 0};                 \
    i32x8 a81 = {av1[0], av1[1], av1[2], av1[3], 0, 0, 0, 0};                 \
    i32x8 a82 = {av2[0], av2[1], av2[2], av2[3], 0, 0, 0, 0};                 \
    i32x8 a83 = {av3[0], av3[1], av3[2], av3[3], 0, 0, 0, 0};                 \
    f32x4 acc0 = {0.f,0.f,0.f,0.f}, acc1 = {0.f,0.f,0.f,0.f};                 \
    f32x4 acc2 = {0.f,0.f,0.f,0.f}, acc3 = {0.f,0.f,0.f,0.f};                 \
    __builtin_amdgcn_s_setprio(1);                                            \
    acc0 = __builtin_amdgcn_mfma_scale_f32_16x16x128_f8f6f4(a80, wgt[0],  acc0, 4, 4, 0, 127, 0, 127); \
    acc1 = __builtin_amdgcn_mfma_scale_f32_16x16x128_f8f6f4(a80, wgt[4],  acc1, 4, 4, 0, 127, 0, 127); \
    acc2 = __builtin_amdgcn_mfma_scale_f32_16x16x128_f8f6f4(a80, wgt[8],  acc2, 4, 4, 0, 127, 0, 127); \
    acc3 = __builtin_amdgcn_mfma_scale_f32_16x16x128_f8f6f4(a80, wgt[12], acc3, 4, 4, 0, 127, 0, 127); \
    acc0 = __builtin_amdgcn_mfma_scale_f32_16x16x128_f8f6f4(a81, wgt[1],  acc0, 4, 4, 0, 127, 0, 127); \
    acc1 = __builtin_amdgcn_mfma_scale_f32_16x16x128_f8f6f4(a81, wgt[5],  acc1, 4, 4, 0, 127, 0, 127); \
    acc2 = __builtin_amdgcn_mfma_scale_f32_16x16x128_f8f6f4(a81, wgt[9],  acc2, 4, 4, 0, 127, 0, 127); \
    acc3 = __builtin_amdgcn_mfma_scale_f32_16x16x128_f8f6f4(a81, wgt[13], acc3, 4, 4, 0, 127, 0, 127); \
    acc0 = __builtin_amdgcn_mfma_scale_f32_16x16x128_f8f6f4(a82, wgt[2],  acc0, 4, 4, 0, 127, 0, 127); \
    acc1 = __builtin_amdgcn_mfma_scale_f32_16x16x128_f8f6f4(a82, wgt[6],  acc1, 4, 4, 0, 127, 0, 127); \
    acc2 = __builtin_amdgcn_mfma_scale_f32_16x16x128_f8f6f4(a82, wgt[10], acc2, 4, 4, 0, 127, 0, 127); \
    acc3 = __builtin_amdgcn_mfma_scale_f32_16x16x128_f8f6f4(a82, wgt[14], acc3, 4, 4, 0, 127, 0, 127); \
    acc0 = __builtin_amdgcn_mfma_scale_f32_16x16x128_f8f6f4(a83, wgt[3],  acc0, 4, 4, 0, 127, 0, 127); \
    acc1 = __builtin_amdgcn_mfma_scale_f32_16x16x128_f8f6f4(a83, wgt[7],  acc1, 4, 4, 0, 127, 0, 127); \
    acc2 = __builtin_amdgcn_mfma_scale_f32_16x16x128_f8f6f4(a83, wgt[11], acc2, 4, 4, 0, 127, 0, 127); \
    acc3 = __builtin_amdgcn_mfma_scale_f32_16x16x128_f8f6f4(a83, wgt[15], acc3, 4, 4, 0, 127, 0, 127); \
    __builtin_amdgcn_s_setprio(0);                                            \
    float av = (q == 0) ? acc0[0] : (q == 1) ? acc1[0] : (q == 2) ? acc2[0] : acc3[0]; \
    float gn = fmaxf(fmaf(av, 1.0f / SW4, h2f(xraw)), 0.f);                   \
    u32 code;                                                                 \
    if (gn < 2.f) code = (u32)(int)rintf(gn * 2.f);                           \
    else if (gn < 4.f) code = 4u + (u32)(int)rintf(gn - 2.f);                 \
    else { u32 c = 6u + (u32)(int)rintf((gn - 4.f) * 0.5f); code = c > 7u ? 7u : c; } \
    u32 pc = (u32)__shfl_xor((int)code, 1);                                   \
    u32 byte = (n16 & 1) ? (pc | (code << 4)) : (code | (pc << 4));           \
    if (wr) greg = byte;                                                      \
    if ((l & 1) == 0) DST[col >> 1] = (unsigned char)greg;                    \
    xraw = xnext;                                                             \
  }

  #pragma unroll 1
  for (int t = 0; t < 512; t += 2){
    RNN_STEP(t, gA, gB);
    __syncthreads();
    RNN_STEP(t + 1, gB, gA);
    __syncthreads();
  }
#undef RNN_STEP

  // ---- fused tail v4: i8 weights + i8 activations, sdot4 ----
  // decode final h (fp4 in gA) -> i8 x4096 (EXACT), packed 4/u32
  if (tid < 128){
    u32 wd = ((const u32*)gA)[tid];
    u32 o0 = 0, o1 = 0;
    #pragma unroll
    for (int j = 0; j < 2; j++){
      u32 byt = (wd >> (8 * j)) & 0xFFu;
      o0 |= fp4i8(byt & 15u) << (16 * j);
      o0 |= fp4i8(byt >> 4) << (16 * j + 8);
    }
    #pragma unroll
    for (int j = 2; j < 4; j++){
      u32 byt = (wd >> (8 * j)) & 0xFFu;
      o1 |= fp4i8(byt & 15u) << (16 * (j - 2));
      o1 |= fp4i8(byt >> 4) << (16 * (j - 2) + 8);
    }
    hi8[2 * tid] = o0;
    hi8[2 * tid + 1] = o1;
  }
  __syncthreads();

  int n0 = 2 * tid;                            // adjacent output columns

  // fc1: K=512 (128 groups). acc scale 4096*1024. -> y1 i8 x8192
  {
    int a0 = 0, a1 = 0;
    #pragma unroll 4
    for (int g = 0; g < 128; g++){
      uint2 w = *(const uint2*)&W1i[g * 1024 + n0];
      u32 hq = hi8[g];
      a0 = dot4(hq, w.x, a0);
      a1 = dot4(hq, w.y, a1);
    }
    float y0 = fmaxf(fmaf((float)a0, 1.0f / 4194304.f, b1[n0]), 0.f);
    float y1v = fmaxf(fmaf((float)a1, 1.0f / 4194304.f, b1[n0 + 1]), 0.f);
    u32 q0 = (u32)(int)fminf(rintf(y0 * 8192.f), 127.f);
    u32 q1 = (u32)(int)fminf(rintf(y1v * 8192.f), 127.f);
    ((u16*)y1i8)[tid] = (u16)(q0 | (q1 << 8));
  }
  __syncthreads();

  // fc2: K=1024 (256 groups). acc scale 8192*1024. -> y2 i8 x8192
  {
    int a0 = 0, a1 = 0;
    #pragma unroll 4
    for (int g = 0; g < 256; g++){
      uint2 w = *(const uint2*)&W2i[g * 1024 + n0];
      u32 hq = y1i8[g];
      a0 = dot4(hq, w.x, a0);
      a1 = dot4(hq, w.y, a1);
    }
    float y0 = fmaxf(fmaf((float)a0, 1.0f / 8388608.f, b2[n0]), 0.f);
    float y1v = fmaxf(fmaf((float)a1, 1.0f / 8388608.f, b2[n0 + 1]), 0.f);
    u32 q0 = (u32)(int)fminf(rintf(y0 * 8192.f), 127.f);
    u32 q1 = (u32)(int)fminf(rintf(y1v * 8192.f), 127.f);
    ((u16*)y2i8)[tid] = (u16)(q0 | (q1 << 8));
  }
  __syncthreads();

  // outz + softmax: thread tid<500 owns logits n0, n0+1
  {
    bool act = tid < 500;
    float z0 = 0.f, z1 = 0.f;
    if (act){
      int a0 = 0, a1 = 0;
      #pragma unroll 4
      for (int g = 0; g < 256; g++){
        uint2 w = *(const uint2*)&Woi[g * 1000 + n0];
        u32 hq = y2i8[g];
        a0 = dot4(hq, w.x, a0);
        a1 = dot4(hq, w.y, a1);
      }
      z0 = fmaf((float)a0, 1.0f / 8388608.f, bo[n0]);
      z1 = fmaf((float)a1, 1.0f / 8388608.f, bo[n0 + 1]);
    }
    float mx = act ? fmaxf(z0, z1) : -1e30f;
    #pragma unroll
    for (int o = 1; o < 64; o <<= 1) mx = fmaxf(mx, __shfl_xor(mx, o));
    if ((tid & 63) == 0) redm[wv] = mx;
    __syncthreads();
    mx = redm[0];
    #pragma unroll
    for (int i = 1; i < 8; i++) mx = fmaxf(mx, redm[i]);
    float e0 = act ? __expf(z0 - mx) : 0.f;
    float e1 = act ? __expf(z1 - mx) : 0.f;
    float s = e0 + e1;
    #pragma unroll
    for (int o = 1; o < 64; o <<= 1) s += __shfl_xor(s, o);
    if ((tid & 63) == 0) reds[wv] = s;
    __syncthreads();
    s = 0.f;
    #pragma unroll
    for (int i = 0; i < 8; i++) s += reds[i];
    float inv = 1.0f / s;
    if (act){
      out[(size_t)b * C_ + n0] = e0 * inv;
      out[(size_t)b * C_ + n0 + 1] = e1 * inv;
    }
  }
}

extern "C" void kernel_launch(void* const* d_in, const int* in_sizes, int n_in,
                              void* d_out, int out_size, void* d_ws, size_t ws_size,
                              hipStream_t stream) {
  const int*   tokens = (const int*)d_in[0];
  const float* emb    = (const float*)d_in[1];
  const float* Wx     = (const float*)d_in[2];
  const float* Wh     = (const float*)d_in[3];
  const float* brnn   = (const float*)d_in[4];
  const float* W1     = (const float*)d_in[5];
  const float* b1     = (const float*)d_in[6];
  const float* W2     = (const float*)d_in[7];
  const float* b2     = (const float*)d_in[8];
  const float* Wo     = (const float*)d_in[9];
  const float* bo     = (const float*)d_in[10];
  float* out = (float*)d_out;

  char* ws = (char*)d_ws;
  size_t off = 0;
  auto alloc = [&](size_t bytes) -> void* {
    void* p = ws + off;
    off += (bytes + 255) & ~(size_t)255;
    return p;
  };
  u16* WxT    = (u16*)alloc((size_t)512 * 512 * 2);
  u16* xpV    = (u16*)alloc((size_t)V_ * 512 * 2);
  uint4* Wf4  = (uint4*)alloc((size_t)128 * 64 * 16);
  u32* W1i    = (u32*)alloc((size_t)128 * 1024 * 4);    // i8-packed W1
  u32* W2i    = (u32*)alloc((size_t)256 * 1024 * 4);    // i8-packed W2
  u32* Woi    = (u32*)alloc((size_t)256 * 1000 * 4);    // i8-packed Wo

  k_prep<<<dim3(96), dim3(256), 0, stream>>>(Wx, WxT, Wh, Wf4);
  k_gemm<<<dim3(1768), dim3(512), 0, stream>>>(emb, WxT, brnn, xpV,
                                               W1, W1i, W2, W2i, Wo, Woi);
  k_rnnt<<<dim3(64), dim3(512), 0, stream>>>(Wf4, xpV, tokens,
                                             W1i, b1, W2i, b2, Woi, bo, out);
}